// Round 3
// baseline (334.032 us; speedup 1.0000x reference)
//
#include <hip/hip_runtime.h>
#include <math.h>

#define NEG_BIG (-1e30f)

typedef __attribute__((ext_vector_type(8))) short short8;
typedef __attribute__((ext_vector_type(8))) _Float16 half8;
typedef __attribute__((ext_vector_type(4))) float floatx4;

__device__ __forceinline__ unsigned short f2bf(float x) {
    unsigned u = __float_as_uint(x);
    unsigned r = (u + 0x7fffu + ((u >> 16) & 1u)) >> 16;
    return (unsigned short)r;
}
__device__ __forceinline__ short f2h(float x) {
    _Float16 h = (_Float16)x;
    return __builtin_bit_cast(short, h);
}
__device__ __forceinline__ float h2f(short s) {
    return (float)__builtin_bit_cast(_Float16, s);
}

// ================= bodies =================

// bonds GEMM: 64 bonds/block, 16 heads, K=512, bf16.
// Self-transposes W_bond (raw [k=512][h=16] fp32) into LDS — no prep dependency.
__device__ __forceinline__ void bonds_body(
    int bbid, char* smem,
    const float* __restrict__ fB, const float* __restrict__ fBo,
    const float* __restrict__ Wb_raw, const float* __restrict__ bb_,
    float* __restrict__ bonds, int Nb)
{
    short* feat = (short*)smem;              // [64][136]
    short* wb   = (short*)(smem + 17408);    // [16][512] chunk-swizzled

    const int tid = threadIdx.x;
    const int j0 = bbid * 64;

    // stage W_bond -> wb[h][k] bf16, chunk-swizzled by h: elem k of head h goes to
    // wb[h*512 + (((k>>3)+h)&63)*8 + (k&7)]
    for (int c = tid; c < 8192; c += 256) {
        int k = c >> 4, h = c & 15;
        wb[h * 512 + ((((k >> 3) + h) & 63) << 3) + (k & 7)] = (short)f2bf(Wb_raw[c]);
    }

    const int wid = tid >> 6, lane = tid & 63;
    const int quad = lane >> 4, l16 = lane & 15;
    floatx4 acc = (floatx4){0.f, 0.f, 0.f, 0.f};

    const int fr = tid >> 2;
    const int fs = (tid & 3) * 32;
    const int j = j0 + fr;

    for (int k0 = 0; k0 < 512; k0 += 128) {
        float x[32];
        if (j < Nb) {
            const float* p = (k0 < 256) ? (fB + (size_t)j * 256 + k0 + fs)
                                        : (fBo + (size_t)j * 256 + (k0 - 256) + fs);
#pragma unroll
            for (int i = 0; i < 8; i++) {
                float4 v = ((const float4*)p)[i];
                x[i * 4 + 0] = v.x; x[i * 4 + 1] = v.y;
                x[i * 4 + 2] = v.z; x[i * 4 + 3] = v.w;
            }
        } else {
#pragma unroll
            for (int i = 0; i < 32; i++) x[i] = 0.f;
        }
        __syncthreads();
#pragma unroll
        for (int c = 0; c < 4; c++) {
            short8 s;
#pragma unroll
            for (int i = 0; i < 8; i++) s[i] = (short)f2bf(x[c * 8 + i]);
            *(short8*)&feat[fr * 136 + fs + c * 8] = s;
        }
        __syncthreads();
#pragma unroll
        for (int kk = 0; kk < 4; kk++) {
            short8 a = *(const short8*)&feat[(wid * 16 + l16) * 136 + kk * 32 + quad * 8];
            int kchunk = (k0 + kk * 32 + quad * 8) >> 3;
            short8 b = *(const short8*)&wb[l16 * 512 + (((kchunk + l16) & 63) * 8)];
            acc = __builtin_amdgcn_mfma_f32_16x16x32_bf16(a, b, acc, 0, 0, 0);
        }
    }
    float bv = bb_[l16];
#pragma unroll
    for (int r = 0; r < 4; r++) {
        int jj = j0 + wid * 16 + quad * 4 + r;
        if (jj < Nb) bonds[(size_t)jj * 16 + l16] = acc[r] + bv;
    }
}

// scatter: last-update-wins via atomicMax on bond index (winner pre-set to -1 by memset)
__device__ __forceinline__ void scatter_body(
    int sbid, char* smem,
    const int* __restrict__ b2a, const int* __restrict__ b2revb,
    const int* __restrict__ b_scope, int* __restrict__ winner,
    int Nb, int Bmol)
{
    int* sb = (int*)smem;
    int tid = threadIdx.x;
    if (tid < Bmol) sb[tid] = b_scope[2 * tid];
    __syncthreads();
    int j = sbid * 256 + tid;
    if (j >= Nb) return;
    int lo = 0, hi = Bmol;
    while (lo < hi) { int mid = (lo + hi) >> 1; if (sb[mid] <= j) lo = mid + 1; else hi = mid; }
    int mol = lo - 1; if (mol < 0) mol = 0;
    int p2 = b2a[j];
    int p1 = b2a[b2revb[j]];
    atomicMax(&winner[mol * 16384 + p1 * 128 + p2], j);
}

// atoms GEMM: fp32 via f16x2 split, 3 MFMA products. tile 128x128, BK=32.
__device__ __forceinline__ void atoms_body(
    int abid, char* smem,
    const float* __restrict__ fA, const float* __restrict__ fAo,
    const int* __restrict__ a_scope,
    const short* __restrict__ WH, const short* __restrict__ WL,
    const float* __restrict__ bias, float* __restrict__ out, int Bmol)
{
    short* A_s = (short*)smem;               // [2][128*40]
    short* B_s = (short*)(smem + 20480);     // [2][128*40]
    int*   rs  = (int*)(smem + 40960);       // [128]

    const int tid = threadIdx.x;
    const int n0 = (abid & 3) * 128;
    const int mol = abid >> 2;

    if (tid < 128) {
        int len = a_scope[2 * mol + 1];
        rs[tid] = (tid < len) ? (a_scope[2 * mol] + tid) : -1;
    }
    const int wid = tid >> 6, lane = tid & 63;
    const int wm = (wid >> 1) * 64, wn = (wid & 1) * 64;
    const int quad = lane >> 4, l16 = lane & 15;

    floatx4 acc1[4][4], acc2[4][4];
#pragma unroll
    for (int i = 0; i < 4; i++)
#pragma unroll
        for (int j = 0; j < 4; j++) {
            acc1[i][j] = (floatx4){0.f, 0.f, 0.f, 0.f};
            acc2[i][j] = (floatx4){0.f, 0.f, 0.f, 0.f};
        }

    const int ar = tid >> 1;
    const int ak = (tid & 1) * 16;
    __syncthreads();                   // rs ready
    const int asrc = rs[ar];

    for (int k0 = 0; k0 < 512; k0 += 32) {
        float x[16];
        if (asrc >= 0) {
            int kg = k0 + ak;
            const float* p = (kg < 256) ? (fA + (size_t)asrc * 256 + kg)
                                        : (fAo + (size_t)asrc * 256 + (kg - 256));
#pragma unroll
            for (int i = 0; i < 4; i++) {
                float4 v = ((const float4*)p)[i];
                x[i * 4 + 0] = v.x; x[i * 4 + 1] = v.y;
                x[i * 4 + 2] = v.z; x[i * 4 + 3] = v.w;
            }
        } else {
#pragma unroll
            for (int i = 0; i < 16; i++) x[i] = 0.f;
        }
        size_t goff = (size_t)(n0 + ar) * 512 + k0 + ak;
        short8 bh0 = *(const short8*)(WH + goff);
        short8 bh1 = *(const short8*)(WH + goff + 8);
        short8 bl0 = *(const short8*)(WL + goff);
        short8 bl1 = *(const short8*)(WL + goff + 8);

        short8 ah0, ah1, al0, al1;
#pragma unroll
        for (int i = 0; i < 8; i++) {
            short h = f2h(x[i]);
            float r = (x[i] - h2f(h)) * 2048.0f;
            ah0[i] = h; al0[i] = f2h(r);
        }
#pragma unroll
        for (int i = 0; i < 8; i++) {
            float xx = x[8 + i];
            short h = f2h(xx);
            float r = (xx - h2f(h)) * 2048.0f;
            ah1[i] = h; al1[i] = f2h(r);
        }

        __syncthreads();
        const int abase = ar * 40 + ak;
        *(short8*)&A_s[abase] = ah0;          *(short8*)&A_s[abase + 8] = ah1;
        *(short8*)&A_s[5120 + abase] = al0;   *(short8*)&A_s[5120 + abase + 8] = al1;
        *(short8*)&B_s[abase] = bh0;          *(short8*)&B_s[abase + 8] = bh1;
        *(short8*)&B_s[5120 + abase] = bl0;   *(short8*)&B_s[5120 + abase + 8] = bl1;
        __syncthreads();

        half8 afh[4], afl[4];
#pragma unroll
        for (int ti = 0; ti < 4; ti++) {
            int off = (wm + ti * 16 + l16) * 40 + quad * 8;
            afh[ti] = *(const half8*)&A_s[off];
            afl[ti] = *(const half8*)&A_s[5120 + off];
        }
#pragma unroll
        for (int tj = 0; tj < 4; tj++) {
            int off = (wn + tj * 16 + l16) * 40 + quad * 8;
            half8 bh = *(const half8*)&B_s[off];
            half8 bl = *(const half8*)&B_s[5120 + off];
#pragma unroll
            for (int ti = 0; ti < 4; ti++) {
                acc1[ti][tj] = __builtin_amdgcn_mfma_f32_16x16x32_f16(afh[ti], bh, acc1[ti][tj], 0, 0, 0);
                acc2[ti][tj] = __builtin_amdgcn_mfma_f32_16x16x32_f16(afh[ti], bl, acc2[ti][tj], 0, 0, 0);
                acc2[ti][tj] = __builtin_amdgcn_mfma_f32_16x16x32_f16(afl[ti], bh, acc2[ti][tj], 0, 0, 0);
            }
        }
    }

#pragma unroll
    for (int tj = 0; tj < 4; tj++) {
        int n = n0 + wn + tj * 16 + l16;
        float bv = bias[n];
#pragma unroll
        for (int ti = 0; ti < 4; ti++) {
#pragma unroll
            for (int r = 0; r < 4; r++) {
                int pos = wm + ti * 16 + quad * 4 + r;
                bool valid = rs[pos] >= 0;
                float v = valid ? (acc1[ti][tj][r] + 4.8828125e-4f * acc2[ti][tj][r] + bv) : 0.f;
                out[((size_t)pos * Bmol + mol) * 512 + n] = v;
            }
        }
    }
}

// out_ap pattern fill: (p2 >= len) ? NEG_BIG : 0, 64 B per thread
__device__ __forceinline__ void fill_body(
    int fbid, const int* __restrict__ a_scope, float* __restrict__ out_ap)
{
    int f = fbid * 256 + threadIdx.x;        // 16-float chunk id
    int r = f >> 3;                          // row: b*2048 + h*128 + p1
    int b = r >> 11;
    int p2b = (f & 7) * 16;
    int len = a_scope[2 * b + 1];
    float4* dst = (float4*)(out_ap + (size_t)f * 16);
#pragma unroll
    for (int c = 0; c < 4; c++) {
        float4 v;
        v.x = (p2b + c * 4 + 0 >= len) ? NEG_BIG : 0.f;
        v.y = (p2b + c * 4 + 1 >= len) ? NEG_BIG : 0.f;
        v.z = (p2b + c * 4 + 2 >= len) ? NEG_BIG : 0.f;
        v.w = (p2b + c * 4 + 3 >= len) ? NEG_BIG : 0.f;
        dst[c] = v;
    }
}

// ================= K1: bonds GEMM | W_atom split | scatter | mask =================
__global__ __launch_bounds__(256) void k_phase1(
    const float* __restrict__ fB, const float* __restrict__ fBo,
    const float* __restrict__ Wb_raw, const float* __restrict__ b_bond,
    float* __restrict__ bonds_ws, int Nb,
    const float* __restrict__ W, short* __restrict__ WH, short* __restrict__ WL,
    const int* __restrict__ b2a, const int* __restrict__ b2revb,
    const int* __restrict__ b_scope, int* __restrict__ winner,
    const int* __restrict__ a_scope, float* __restrict__ mask_out,
    int Bmol, int nBondsB, int nScatB)
{
    __shared__ char smem[33792];
    int bid = blockIdx.x;
    int tid = threadIdx.x;
    if (bid < nBondsB) {
        bonds_body(bid, smem, fB, fBo, Wb_raw, b_bond, bonds_ws, Nb);
        return;
    }
    bid -= nBondsB;
    if (bid < 1024) {
        // W_atom f16x2 split, [k][n] -> [n][k]
        int t = bid * 256 + tid;            // 262144
        int n = t >> 9, k = t & 511;
        float x = W[(size_t)k * 512 + n];
        short h = f2h(x);
        float r = (x - h2f(h)) * 2048.0f;
        WH[t] = h;
        WL[t] = f2h(r);
        return;
    }
    bid -= 1024;
    if (bid < nScatB) {
        scatter_body(bid, smem, b2a, b2revb, b_scope, winner, Nb, Bmol);
        return;
    }
    bid -= nScatB;
    {
        int t = bid * 256 + tid;
        if (t < Bmol * 128) {
            int b = t >> 7, p = t & 127;
            mask_out[t] = (p >= a_scope[2 * b + 1]) ? 1.0f : 0.0f;
        }
    }
}

// ================= K2: atoms GEMM | out_ap fill =================
__global__ __launch_bounds__(256, 2) void k_phase2(
    const float* __restrict__ fA, const float* __restrict__ fAo,
    const int* __restrict__ a_scope,
    const short* __restrict__ WH, const short* __restrict__ WL,
    const float* __restrict__ b_atom,
    float* __restrict__ out_emb, float* __restrict__ out_ap,
    int Bmol, int nAtomsB)
{
    __shared__ char smem[41472];
    int bid = blockIdx.x;
    if (bid < nAtomsB) {
        atoms_body(bid, smem, fA, fAo, a_scope, WH, WL, b_atom, out_emb, Bmol);
        return;
    }
    fill_body(bid - nAtomsB, a_scope, out_ap);
}

// ================= K3: commit winner bonds, 16 threads/bond =================
__global__ __launch_bounds__(256) void k_commit(
    const int* __restrict__ b2a, const int* __restrict__ b2revb,
    const int* __restrict__ b_scope, const int* __restrict__ a_scope,
    const int* __restrict__ winner, const float* __restrict__ bonds,
    float* __restrict__ out_ap, int Nb, int Bmol)
{
    __shared__ int sb[128];
    int tid = threadIdx.x;
    if (tid < Bmol) sb[tid] = b_scope[2 * tid];
    __syncthreads();
    int t = blockIdx.x * 256 + tid;
    int j = t >> 4, h = t & 15;
    if (j >= Nb) return;
    int lo = 0, hi = Bmol;
    while (lo < hi) { int mid = (lo + hi) >> 1; if (sb[mid] <= j) lo = mid + 1; else hi = mid; }
    int mol = lo - 1; if (mol < 0) mol = 0;
    int p2 = b2a[j];
    int p1 = b2a[b2revb[j]];
    int cell = mol * 16384 + p1 * 128 + p2;
    if (winner[cell] != j) return;
    if (p2 >= a_scope[2 * mol + 1]) return;   // reference masks these cells after scatter
    out_ap[(((size_t)mol * 16 + h) * 128 + p1) * 128 + p2] = bonds[(size_t)j * 16 + h];
}

extern "C" void kernel_launch(void* const* d_in, const int* in_sizes, int n_in,
                              void* d_out, int out_size, void* d_ws, size_t ws_size,
                              hipStream_t stream)
{
    const float* f_atoms     = (const float*)d_in[0];
    const float* f_bonds     = (const float*)d_in[1];
    const float* f_atoms_out = (const float*)d_in[2];
    const float* f_bonds_out = (const float*)d_in[3];
    const int*   b2a         = (const int*)d_in[4];
    const int*   b2revb      = (const int*)d_in[5];
    const int*   a_scope     = (const int*)d_in[6];
    const int*   b_scope     = (const int*)d_in[7];
    const float* W_atom      = (const float*)d_in[9];
    const float* b_atom      = (const float*)d_in[10];
    const float* W_bond      = (const float*)d_in[11];
    const float* b_bond      = (const float*)d_in[12];

    const int Bmol = in_sizes[6] / 2;   // 128
    const int Nb   = in_sizes[4];

    char* ws = (char*)d_ws;
    size_t off = 0;
    float* bonds_ws = (float*)(ws + off); off += ((size_t)Nb * 16 * 4 + 255) & ~(size_t)255;
    int*   winner   = (int*)(ws + off);   off += (size_t)Bmol * 16384 * 4;
    short* WH       = (short*)(ws + off); off += 512 * 512 * 2;
    short* WL       = (short*)(ws + off); off += 512 * 512 * 2;

    float* out_emb  = (float*)d_out;                                // (128, B, 512)
    float* out_ap   = out_emb + (size_t)128 * Bmol * 512;           // (B, 16, 128, 128)
    float* out_mask = out_ap + (size_t)Bmol * 16 * 128 * 128;       // (B, 128)

    // winner = -1 via byte pattern 0xFF (graph-capturable memset node)
    hipMemsetAsync(winner, 0xFF, (size_t)Bmol * 16384 * 4, stream);

    // K1: bonds GEMM | W_atom split | scatter | mask
    const int nBondsB = (Nb + 63) / 64;
    const int nScatB  = (Nb + 255) / 256;
    const int nMaskB  = (Bmol * 128 + 255) / 256;
    hipLaunchKernelGGL(k_phase1, dim3(nBondsB + 1024 + nScatB + nMaskB), dim3(256), 0, stream,
                       f_bonds, f_bonds_out, W_bond, b_bond, bonds_ws, Nb,
                       W_atom, WH, WL,
                       b2a, b2revb, b_scope, winner,
                       a_scope, out_mask, Bmol, nBondsB, nScatB);

    // K2: atoms GEMM | out_ap pattern fill
    const int nAtomsB = 4 * Bmol;
    const int nFillB  = Bmol * 64;
    hipLaunchKernelGGL(k_phase2, dim3(nAtomsB + nFillB), dim3(256), 0, stream,
                       f_atoms, f_atoms_out, a_scope, WH, WL, b_atom,
                       out_emb, out_ap, Bmol, nAtomsB);

    // K3: commit winning bonds (16 threads per bond)
    hipLaunchKernelGGL(k_commit, dim3((Nb * 16 + 255) / 256), dim3(256), 0, stream,
                       b2a, b2revb, b_scope, a_scope, winner, bonds_ws, out_ap, Nb, Bmol);
}

// Round 4
// 299.414 us; speedup vs baseline: 1.1156x; 1.1156x over previous
//
#include <hip/hip_runtime.h>
#include <math.h>

#define NEG_BIG (-1e30f)

typedef __attribute__((ext_vector_type(8))) short short8;
typedef __attribute__((ext_vector_type(8))) _Float16 half8;
typedef __attribute__((ext_vector_type(4))) float floatx4;

__device__ __forceinline__ unsigned short f2bf(float x) {
    unsigned u = __float_as_uint(x);
    unsigned r = (u + 0x7fffu + ((u >> 16) & 1u)) >> 16;
    return (unsigned short)r;
}
__device__ __forceinline__ short f2h(float x) {
    _Float16 h = (_Float16)x;
    return __builtin_bit_cast(short, h);
}
__device__ __forceinline__ float h2f(short s) {
    return (float)__builtin_bit_cast(_Float16, s);
}

// ================= bodies =================

// bonds GEMM: 64 bonds/block, 16 heads, K=512, bf16.
// Self-transposes W_bond (raw [k=512][h=16] fp32) into LDS — no prep dependency.
__device__ __forceinline__ void bonds_body(
    int bbid, char* smem,
    const float* __restrict__ fB, const float* __restrict__ fBo,
    const float* __restrict__ Wb_raw, const float* __restrict__ bb_,
    float* __restrict__ bonds, int Nb)
{
    short* feat = (short*)smem;              // [64][136]
    short* wb   = (short*)(smem + 17408);    // [16][512] chunk-swizzled

    const int tid = threadIdx.x;
    const int j0 = bbid * 64;

    // stage W_bond -> wb[h][k] bf16, chunk-swizzled by h
    for (int c = tid; c < 8192; c += 256) {
        int k = c >> 4, h = c & 15;
        wb[h * 512 + ((((k >> 3) + h) & 63) << 3) + (k & 7)] = (short)f2bf(Wb_raw[c]);
    }

    const int wid = tid >> 6, lane = tid & 63;
    const int quad = lane >> 4, l16 = lane & 15;
    floatx4 acc = (floatx4){0.f, 0.f, 0.f, 0.f};

    const int fr = tid >> 2;
    const int fs = (tid & 3) * 32;
    const int j = j0 + fr;

    for (int k0 = 0; k0 < 512; k0 += 128) {
        float x[32];
        if (j < Nb) {
            const float* p = (k0 < 256) ? (fB + (size_t)j * 256 + k0 + fs)
                                        : (fBo + (size_t)j * 256 + (k0 - 256) + fs);
#pragma unroll
            for (int i = 0; i < 8; i++) {
                float4 v = ((const float4*)p)[i];
                x[i * 4 + 0] = v.x; x[i * 4 + 1] = v.y;
                x[i * 4 + 2] = v.z; x[i * 4 + 3] = v.w;
            }
        } else {
#pragma unroll
            for (int i = 0; i < 32; i++) x[i] = 0.f;
        }
        __syncthreads();
#pragma unroll
        for (int c = 0; c < 4; c++) {
            short8 s;
#pragma unroll
            for (int i = 0; i < 8; i++) s[i] = (short)f2bf(x[c * 8 + i]);
            *(short8*)&feat[fr * 136 + fs + c * 8] = s;
        }
        __syncthreads();
#pragma unroll
        for (int kk = 0; kk < 4; kk++) {
            short8 a = *(const short8*)&feat[(wid * 16 + l16) * 136 + kk * 32 + quad * 8];
            int kchunk = (k0 + kk * 32 + quad * 8) >> 3;
            short8 b = *(const short8*)&wb[l16 * 512 + (((kchunk + l16) & 63) * 8)];
            acc = __builtin_amdgcn_mfma_f32_16x16x32_bf16(a, b, acc, 0, 0, 0);
        }
    }
    float bv = bb_[l16];
#pragma unroll
    for (int r = 0; r < 4; r++) {
        int jj = j0 + wid * 16 + quad * 4 + r;
        if (jj < Nb) bonds[(size_t)jj * 16 + l16] = acc[r] + bv;
    }
}

// scatter: last-update-wins via atomicMax on bond index (winner pre-set to -1 by memset)
__device__ __forceinline__ void scatter_body(
    int sbid, char* smem,
    const int* __restrict__ b2a, const int* __restrict__ b2revb,
    const int* __restrict__ b_scope, int* __restrict__ winner,
    int Nb, int Bmol)
{
    int* sb = (int*)smem;
    int tid = threadIdx.x;
    if (tid < Bmol) sb[tid] = b_scope[2 * tid];
    __syncthreads();
    int j = sbid * 256 + tid;
    if (j >= Nb) return;
    int lo = 0, hi = Bmol;
    while (lo < hi) { int mid = (lo + hi) >> 1; if (sb[mid] <= j) lo = mid + 1; else hi = mid; }
    int mol = lo - 1; if (mol < 0) mol = 0;
    int p2 = b2a[j];
    int p1 = b2a[b2revb[j]];
    atomicMax(&winner[mol * 16384 + p1 * 128 + p2], j);
}

// atoms GEMM: fp32 via f16x2 split, 3 MFMA products. tile 128x128, BK=32.
__device__ __forceinline__ void atoms_body(
    int abid, char* smem,
    const float* __restrict__ fA, const float* __restrict__ fAo,
    const int* __restrict__ a_scope,
    const short* __restrict__ WH, const short* __restrict__ WL,
    const float* __restrict__ bias, float* __restrict__ out, int Bmol)
{
    short* A_s = (short*)smem;               // [2][128*40]
    short* B_s = (short*)(smem + 20480);     // [2][128*40]
    int*   rs  = (int*)(smem + 40960);       // [128]

    const int tid = threadIdx.x;
    const int n0 = (abid & 3) * 128;
    const int mol = abid >> 2;

    if (tid < 128) {
        int len = a_scope[2 * mol + 1];
        rs[tid] = (tid < len) ? (a_scope[2 * mol] + tid) : -1;
    }
    const int wid = tid >> 6, lane = tid & 63;
    const int wm = (wid >> 1) * 64, wn = (wid & 1) * 64;
    const int quad = lane >> 4, l16 = lane & 15;

    floatx4 acc1[4][4], acc2[4][4];
#pragma unroll
    for (int i = 0; i < 4; i++)
#pragma unroll
        for (int j = 0; j < 4; j++) {
            acc1[i][j] = (floatx4){0.f, 0.f, 0.f, 0.f};
            acc2[i][j] = (floatx4){0.f, 0.f, 0.f, 0.f};
        }

    const int ar = tid >> 1;
    const int ak = (tid & 1) * 16;
    __syncthreads();                   // rs ready
    const int asrc = rs[ar];

    for (int k0 = 0; k0 < 512; k0 += 32) {
        float x[16];
        if (asrc >= 0) {
            int kg = k0 + ak;
            const float* p = (kg < 256) ? (fA + (size_t)asrc * 256 + kg)
                                        : (fAo + (size_t)asrc * 256 + (kg - 256));
#pragma unroll
            for (int i = 0; i < 4; i++) {
                float4 v = ((const float4*)p)[i];
                x[i * 4 + 0] = v.x; x[i * 4 + 1] = v.y;
                x[i * 4 + 2] = v.z; x[i * 4 + 3] = v.w;
            }
        } else {
#pragma unroll
            for (int i = 0; i < 16; i++) x[i] = 0.f;
        }
        size_t goff = (size_t)(n0 + ar) * 512 + k0 + ak;
        short8 bh0 = *(const short8*)(WH + goff);
        short8 bh1 = *(const short8*)(WH + goff + 8);
        short8 bl0 = *(const short8*)(WL + goff);
        short8 bl1 = *(const short8*)(WL + goff + 8);

        short8 ah0, ah1, al0, al1;
#pragma unroll
        for (int i = 0; i < 8; i++) {
            short h = f2h(x[i]);
            float r = (x[i] - h2f(h)) * 2048.0f;
            ah0[i] = h; al0[i] = f2h(r);
        }
#pragma unroll
        for (int i = 0; i < 8; i++) {
            float xx = x[8 + i];
            short h = f2h(xx);
            float r = (xx - h2f(h)) * 2048.0f;
            ah1[i] = h; al1[i] = f2h(r);
        }

        __syncthreads();
        const int abase = ar * 40 + ak;
        *(short8*)&A_s[abase] = ah0;          *(short8*)&A_s[abase + 8] = ah1;
        *(short8*)&A_s[5120 + abase] = al0;   *(short8*)&A_s[5120 + abase + 8] = al1;
        *(short8*)&B_s[abase] = bh0;          *(short8*)&B_s[abase + 8] = bh1;
        *(short8*)&B_s[5120 + abase] = bl0;   *(short8*)&B_s[5120 + abase + 8] = bl1;
        __syncthreads();

        half8 afh[4], afl[4];
#pragma unroll
        for (int ti = 0; ti < 4; ti++) {
            int off = (wm + ti * 16 + l16) * 40 + quad * 8;
            afh[ti] = *(const half8*)&A_s[off];
            afl[ti] = *(const half8*)&A_s[5120 + off];
        }
#pragma unroll
        for (int tj = 0; tj < 4; tj++) {
            int off = (wn + tj * 16 + l16) * 40 + quad * 8;
            half8 bh = *(const half8*)&B_s[off];
            half8 bl = *(const half8*)&B_s[5120 + off];
#pragma unroll
            for (int ti = 0; ti < 4; ti++) {
                acc1[ti][tj] = __builtin_amdgcn_mfma_f32_16x16x32_f16(afh[ti], bh, acc1[ti][tj], 0, 0, 0);
                acc2[ti][tj] = __builtin_amdgcn_mfma_f32_16x16x32_f16(afh[ti], bl, acc2[ti][tj], 0, 0, 0);
                acc2[ti][tj] = __builtin_amdgcn_mfma_f32_16x16x32_f16(afl[ti], bh, acc2[ti][tj], 0, 0, 0);
            }
        }
    }

#pragma unroll
    for (int tj = 0; tj < 4; tj++) {
        int n = n0 + wn + tj * 16 + l16;
        float bv = bias[n];
#pragma unroll
        for (int ti = 0; ti < 4; ti++) {
#pragma unroll
            for (int r = 0; r < 4; r++) {
                int pos = wm + ti * 16 + quad * 4 + r;
                bool valid = rs[pos] >= 0;
                float v = valid ? (acc1[ti][tj][r] + 4.8828125e-4f * acc2[ti][tj][r] + bv) : 0.f;
                out[((size_t)pos * Bmol + mol) * 512 + n] = v;
            }
        }
    }
}

// apairs one-pass gather: winner int4 + bonds gather -> 134 MB write, once.
__device__ __forceinline__ void apairs_body(
    int chunk, const int* __restrict__ winner, const float* __restrict__ bonds,
    const int* __restrict__ a_scope, float* __restrict__ out_ap)
{
    int t = chunk * 256 + threadIdx.x;
    int b = t >> 12;
    int p1 = (t >> 5) & 127;
    int p2q = t & 31;
    int len = a_scope[2 * b + 1];
    const int4 w = ((const int4*)winner)[t];

    int wi0 = w.x, wi1 = w.y, wi2 = w.z, wi3 = w.w;
    float rows[4][16];
#pragma unroll
    for (int c = 0; c < 16; c++) {
        rows[0][c] = 0.f; rows[1][c] = 0.f; rows[2][c] = 0.f; rows[3][c] = 0.f;
    }
    if (wi0 >= 0) {
        const float4* p = (const float4*)(bonds + (size_t)wi0 * 16);
#pragma unroll
        for (int c = 0; c < 4; c++) {
            float4 v = p[c];
            rows[0][4*c+0] = v.x; rows[0][4*c+1] = v.y; rows[0][4*c+2] = v.z; rows[0][4*c+3] = v.w;
        }
    }
    if (wi1 >= 0) {
        const float4* p = (const float4*)(bonds + (size_t)wi1 * 16);
#pragma unroll
        for (int c = 0; c < 4; c++) {
            float4 v = p[c];
            rows[1][4*c+0] = v.x; rows[1][4*c+1] = v.y; rows[1][4*c+2] = v.z; rows[1][4*c+3] = v.w;
        }
    }
    if (wi2 >= 0) {
        const float4* p = (const float4*)(bonds + (size_t)wi2 * 16);
#pragma unroll
        for (int c = 0; c < 4; c++) {
            float4 v = p[c];
            rows[2][4*c+0] = v.x; rows[2][4*c+1] = v.y; rows[2][4*c+2] = v.z; rows[2][4*c+3] = v.w;
        }
    }
    if (wi3 >= 0) {
        const float4* p = (const float4*)(bonds + (size_t)wi3 * 16);
#pragma unroll
        for (int c = 0; c < 4; c++) {
            float4 v = p[c];
            rows[3][4*c+0] = v.x; rows[3][4*c+1] = v.y; rows[3][4*c+2] = v.z; rows[3][4*c+3] = v.w;
        }
    }

    bool iv0 = (p2q * 4 + 0 >= len);
    bool iv1 = (p2q * 4 + 1 >= len);
    bool iv2 = (p2q * 4 + 2 >= len);
    bool iv3 = (p2q * 4 + 3 >= len);
    float* ob = out_ap + ((size_t)b * 16 * 128 + p1) * 128 + p2q * 4;
#pragma unroll
    for (int h = 0; h < 16; h++) {
        float4 v;
        v.x = iv0 ? NEG_BIG : rows[0][h];
        v.y = iv1 ? NEG_BIG : rows[1][h];
        v.z = iv2 ? NEG_BIG : rows[2][h];
        v.w = iv3 ? NEG_BIG : rows[3][h];
        *(float4*)(ob + (size_t)h * 16384) = v;
    }
}

// ================= K1: bonds GEMM | W_atom split | scatter | mask =================
__global__ __launch_bounds__(256) void k_phase1(
    const float* __restrict__ fB, const float* __restrict__ fBo,
    const float* __restrict__ Wb_raw, const float* __restrict__ b_bond,
    float* __restrict__ bonds_ws, int Nb,
    const float* __restrict__ W, short* __restrict__ WH, short* __restrict__ WL,
    const int* __restrict__ b2a, const int* __restrict__ b2revb,
    const int* __restrict__ b_scope, int* __restrict__ winner,
    const int* __restrict__ a_scope, float* __restrict__ mask_out,
    int Bmol, int nBondsB, int nScatB)
{
    __shared__ char smem[33792];
    int bid = blockIdx.x;
    int tid = threadIdx.x;
    if (bid < nBondsB) {
        bonds_body(bid, smem, fB, fBo, Wb_raw, b_bond, bonds_ws, Nb);
        return;
    }
    bid -= nBondsB;
    if (bid < 1024) {
        // W_atom f16x2 split, [k][n] -> [n][k]
        int t = bid * 256 + tid;            // 262144
        int n = t >> 9, k = t & 511;
        float x = W[(size_t)k * 512 + n];
        short h = f2h(x);
        float r = (x - h2f(h)) * 2048.0f;
        WH[t] = h;
        WL[t] = f2h(r);
        return;
    }
    bid -= 1024;
    if (bid < nScatB) {
        scatter_body(bid, smem, b2a, b2revb, b_scope, winner, Nb, Bmol);
        return;
    }
    bid -= nScatB;
    {
        int t = bid * 256 + tid;
        if (t < Bmol * 128) {
            int b = t >> 7, p = t & 127;
            mask_out[t] = (p >= a_scope[2 * b + 1]) ? 1.0f : 0.0f;
        }
    }
}

// ================= K2: atoms GEMM staggered with one-pass apairs =================
// block b does 5 jobs: its atoms tile at slot (b&3), and 4 apairs chunks.
// => ~1/4 of blocks on the matrix pipe while ~3/4 stream the 134 MB write.
__global__ __launch_bounds__(256, 2) void k_phase2(
    const float* __restrict__ fA, const float* __restrict__ fAo,
    const int* __restrict__ a_scope,
    const short* __restrict__ WH, const short* __restrict__ WL,
    const float* __restrict__ b_atom,
    const int* __restrict__ winner, const float* __restrict__ bonds_ws,
    float* __restrict__ out_emb, float* __restrict__ out_ap,
    int Bmol)
{
    __shared__ char smem[41472];
    const int bid = blockIdx.x;          // 0 .. 4*Bmol-1
    const int s = bid & 3;
    int ai = 0;
#pragma unroll
    for (int r = 0; r < 5; r++) {
        if (r == s) {
            atoms_body(bid, smem, fA, fAo, a_scope, WH, WL, b_atom, out_emb, Bmol);
        } else {
            apairs_body(bid * 4 + ai, winner, bonds_ws, a_scope, out_ap);
            ai++;
        }
    }
}

extern "C" void kernel_launch(void* const* d_in, const int* in_sizes, int n_in,
                              void* d_out, int out_size, void* d_ws, size_t ws_size,
                              hipStream_t stream)
{
    const float* f_atoms     = (const float*)d_in[0];
    const float* f_bonds     = (const float*)d_in[1];
    const float* f_atoms_out = (const float*)d_in[2];
    const float* f_bonds_out = (const float*)d_in[3];
    const int*   b2a         = (const int*)d_in[4];
    const int*   b2revb      = (const int*)d_in[5];
    const int*   a_scope     = (const int*)d_in[6];
    const int*   b_scope     = (const int*)d_in[7];
    const float* W_atom      = (const float*)d_in[9];
    const float* b_atom      = (const float*)d_in[10];
    const float* W_bond      = (const float*)d_in[11];
    const float* b_bond      = (const float*)d_in[12];

    const int Bmol = in_sizes[6] / 2;   // 128
    const int Nb   = in_sizes[4];

    char* ws = (char*)d_ws;
    size_t off = 0;
    float* bonds_ws = (float*)(ws + off); off += ((size_t)Nb * 16 * 4 + 255) & ~(size_t)255;
    int*   winner   = (int*)(ws + off);   off += (size_t)Bmol * 16384 * 4;
    short* WH       = (short*)(ws + off); off += 512 * 512 * 2;
    short* WL       = (short*)(ws + off); off += 512 * 512 * 2;

    float* out_emb  = (float*)d_out;                                // (128, B, 512)
    float* out_ap   = out_emb + (size_t)128 * Bmol * 512;           // (B, 16, 128, 128)
    float* out_mask = out_ap + (size_t)Bmol * 16 * 128 * 128;       // (B, 128)

    // winner = -1 via byte pattern 0xFF (graph-capturable memset node)
    hipMemsetAsync(winner, 0xFF, (size_t)Bmol * 16384 * 4, stream);

    // K1: bonds GEMM | W_atom split | scatter | mask
    const int nBondsB = (Nb + 63) / 64;
    const int nScatB  = (Nb + 255) / 256;
    const int nMaskB  = (Bmol * 128 + 255) / 256;
    hipLaunchKernelGGL(k_phase1, dim3(nBondsB + 1024 + nScatB + nMaskB), dim3(256), 0, stream,
                       f_bonds, f_bonds_out, W_bond, b_bond, bonds_ws, Nb,
                       W_atom, WH, WL,
                       b2a, b2revb, b_scope, winner,
                       a_scope, out_mask, Bmol, nBondsB, nScatB);

    // K2: atoms GEMM staggered with one-pass apairs gather/write
    hipLaunchKernelGGL(k_phase2, dim3(4 * Bmol), dim3(256), 0, stream,
                       f_atoms, f_atoms_out, a_scope, WH, WL, b_atom,
                       winner, bonds_ws, out_emb, out_ap, Bmol);
}

// Round 5
// 297.434 us; speedup vs baseline: 1.1230x; 1.0067x over previous
//
#include <hip/hip_runtime.h>
#include <math.h>

#define NEG_BIG (-1e30f)

typedef __attribute__((ext_vector_type(8))) short short8;
typedef __attribute__((ext_vector_type(8))) _Float16 half8;
typedef __attribute__((ext_vector_type(4))) float floatx4;

__device__ __forceinline__ unsigned short f2bf(float x) {
    unsigned u = __float_as_uint(x);
    unsigned r = (u + 0x7fffu + ((u >> 16) & 1u)) >> 16;
    return (unsigned short)r;
}
__device__ __forceinline__ short f2h(float x) {
    _Float16 h = (_Float16)x;
    return __builtin_bit_cast(short, h);
}
__device__ __forceinline__ float h2f(short s) {
    return (float)__builtin_bit_cast(_Float16, s);
}

// ================= bodies =================

// bonds GEMM: 64 bonds/block, 16 heads, K=512, bf16.
// Self-transposes W_bond (raw [k=512][h=16] fp32) into LDS.
__device__ __forceinline__ void bonds_body(
    int bbid, char* smem,
    const float* __restrict__ fB, const float* __restrict__ fBo,
    const float* __restrict__ Wb_raw, const float* __restrict__ bb_,
    float* __restrict__ bonds, int Nb)
{
    short* feat = (short*)smem;              // [64][136]
    short* wb   = (short*)(smem + 17408);    // [16][512] chunk-swizzled

    const int tid = threadIdx.x;
    const int j0 = bbid * 64;

    for (int c = tid; c < 8192; c += 256) {
        int k = c >> 4, h = c & 15;
        wb[h * 512 + ((((k >> 3) + h) & 63) << 3) + (k & 7)] = (short)f2bf(Wb_raw[c]);
    }

    const int wid = tid >> 6, lane = tid & 63;
    const int quad = lane >> 4, l16 = lane & 15;
    floatx4 acc = (floatx4){0.f, 0.f, 0.f, 0.f};

    const int fr = tid >> 2;
    const int fs = (tid & 3) * 32;
    const int j = j0 + fr;

    for (int k0 = 0; k0 < 512; k0 += 128) {
        float x[32];
        if (j < Nb) {
            const float* p = (k0 < 256) ? (fB + (size_t)j * 256 + k0 + fs)
                                        : (fBo + (size_t)j * 256 + (k0 - 256) + fs);
#pragma unroll
            for (int i = 0; i < 8; i++) {
                float4 v = ((const float4*)p)[i];
                x[i * 4 + 0] = v.x; x[i * 4 + 1] = v.y;
                x[i * 4 + 2] = v.z; x[i * 4 + 3] = v.w;
            }
        } else {
#pragma unroll
            for (int i = 0; i < 32; i++) x[i] = 0.f;
        }
        __syncthreads();
#pragma unroll
        for (int c = 0; c < 4; c++) {
            short8 s;
#pragma unroll
            for (int i = 0; i < 8; i++) s[i] = (short)f2bf(x[c * 8 + i]);
            *(short8*)&feat[fr * 136 + fs + c * 8] = s;
        }
        __syncthreads();
#pragma unroll
        for (int kk = 0; kk < 4; kk++) {
            short8 a = *(const short8*)&feat[(wid * 16 + l16) * 136 + kk * 32 + quad * 8];
            int kchunk = (k0 + kk * 32 + quad * 8) >> 3;
            short8 b = *(const short8*)&wb[l16 * 512 + (((kchunk + l16) & 63) * 8)];
            acc = __builtin_amdgcn_mfma_f32_16x16x32_bf16(a, b, acc, 0, 0, 0);
        }
    }
    float bv = bb_[l16];
#pragma unroll
    for (int r = 0; r < 4; r++) {
        int jj = j0 + wid * 16 + quad * 4 + r;
        if (jj < Nb) bonds[(size_t)jj * 16 + l16] = acc[r] + bv;
    }
}

// scatter: last-update-wins via atomicMax (winner pre-set -1 by memset)
__device__ __forceinline__ void scatter_body(
    int sbid, char* smem,
    const int* __restrict__ b2a, const int* __restrict__ b2revb,
    const int* __restrict__ b_scope, int* __restrict__ winner,
    int Nb, int Bmol)
{
    int* sb = (int*)smem;
    int tid = threadIdx.x;
    if (tid < Bmol) sb[tid] = b_scope[2 * tid];
    __syncthreads();
    int j = sbid * 256 + tid;
    if (j >= Nb) return;
    int lo = 0, hi = Bmol;
    while (lo < hi) { int mid = (lo + hi) >> 1; if (sb[mid] <= j) lo = mid + 1; else hi = mid; }
    int mol = lo - 1; if (mol < 0) mol = 0;
    int p2 = b2a[j];
    int p1 = b2a[b2revb[j]];
    atomicMax(&winner[mol * 16384 + p1 * 128 + p2], j);
}

// atoms GEMM, ZERO-LDS: operands pre-laid-out in MFMA fragment order.
// Frag chunk layout (both A and B): elem (r,k) at [(rt*64+kq)*128 + l16*8 + e]
// with r=rt*16+l16, k=kq*8+e. A wave's frag load (quad,l16) = one coalesced 1KB dwordx4.
__device__ __forceinline__ void atoms_body(
    int abid,
    const int* __restrict__ a_scope,
    const short* __restrict__ AHf, const short* __restrict__ ALf,
    const short* __restrict__ WHf, const short* __restrict__ WLf,
    const float* __restrict__ bias, float* __restrict__ out, int Bmol)
{
    const int tid = threadIdx.x;
    const int mol = abid >> 2;
    const int n0 = (abid & 3) * 128;
    const int wid = tid >> 6, lane = tid & 63;
    const int wm = (wid >> 1) * 64, wn = (wid & 1) * 64;
    const int quad = lane >> 4, l16 = lane & 15;
    const int len = a_scope[2 * mol + 1];

    const int laneoff = quad * 128 + l16 * 8;
    const short* __restrict__ Ah = AHf + (size_t)mol * 65536 + (wm >> 4) * 8192 + laneoff;
    const short* __restrict__ Al = ALf + (size_t)mol * 65536 + (wm >> 4) * 8192 + laneoff;
    const short* __restrict__ Bh = WHf + ((n0 + wn) >> 4) * 8192 + laneoff;
    const short* __restrict__ Bl = WLf + ((n0 + wn) >> 4) * 8192 + laneoff;

    floatx4 acc1[4][4], acc2[4][4];
#pragma unroll
    for (int i = 0; i < 4; i++)
#pragma unroll
        for (int j = 0; j < 4; j++) {
            acc1[i][j] = (floatx4){0.f, 0.f, 0.f, 0.f};
            acc2[i][j] = (floatx4){0.f, 0.f, 0.f, 0.f};
        }

    for (int k0 = 0; k0 < 512; k0 += 32) {
        const int koff = k0 * 16;     // (k0>>3)*128 elems
        half8 ah[4], al[4], bh[4], bl[4];
#pragma unroll
        for (int ti = 0; ti < 4; ti++) {
            ah[ti] = *(const half8*)(Ah + ti * 8192 + koff);
            al[ti] = *(const half8*)(Al + ti * 8192 + koff);
        }
#pragma unroll
        for (int tj = 0; tj < 4; tj++) {
            bh[tj] = *(const half8*)(Bh + tj * 8192 + koff);
            bl[tj] = *(const half8*)(Bl + tj * 8192 + koff);
        }
#pragma unroll
        for (int tj = 0; tj < 4; tj++) {
#pragma unroll
            for (int ti = 0; ti < 4; ti++) {
                acc1[ti][tj] = __builtin_amdgcn_mfma_f32_16x16x32_f16(ah[ti], bh[tj], acc1[ti][tj], 0, 0, 0);
                acc2[ti][tj] = __builtin_amdgcn_mfma_f32_16x16x32_f16(ah[ti], bl[tj], acc2[ti][tj], 0, 0, 0);
                acc2[ti][tj] = __builtin_amdgcn_mfma_f32_16x16x32_f16(al[ti], bh[tj], acc2[ti][tj], 0, 0, 0);
            }
        }
    }

    // epilogue: D col = lane&15, row = quad*4+reg (m89-verified layout)
#pragma unroll
    for (int tj = 0; tj < 4; tj++) {
        int n = n0 + wn + tj * 16 + l16;
        float bv = bias[n];
#pragma unroll
        for (int ti = 0; ti < 4; ti++) {
#pragma unroll
            for (int r = 0; r < 4; r++) {
                int pos = wm + ti * 16 + quad * 4 + r;
                bool valid = pos < len;
                float v = valid ? (acc1[ti][tj][r] + 4.8828125e-4f * acc2[ti][tj][r] + bv) : 0.f;
                out[((size_t)pos * Bmol + mol) * 512 + n] = v;
            }
        }
    }
}

// apairs one-pass gather: winner int4 + bonds gather -> 134 MB write, once.
__device__ __forceinline__ void apairs_body(
    int chunk, const int* __restrict__ winner, const float* __restrict__ bonds,
    const int* __restrict__ a_scope, float* __restrict__ out_ap)
{
    int t = chunk * 256 + threadIdx.x;
    int b = t >> 12;
    int p1 = (t >> 5) & 127;
    int p2q = t & 31;
    int len = a_scope[2 * b + 1];
    const int4 w = ((const int4*)winner)[t];

    int wi0 = w.x, wi1 = w.y, wi2 = w.z, wi3 = w.w;
    float rows[4][16];
#pragma unroll
    for (int c = 0; c < 16; c++) {
        rows[0][c] = 0.f; rows[1][c] = 0.f; rows[2][c] = 0.f; rows[3][c] = 0.f;
    }
    if (wi0 >= 0) {
        const float4* p = (const float4*)(bonds + (size_t)wi0 * 16);
#pragma unroll
        for (int c = 0; c < 4; c++) {
            float4 v = p[c];
            rows[0][4*c+0] = v.x; rows[0][4*c+1] = v.y; rows[0][4*c+2] = v.z; rows[0][4*c+3] = v.w;
        }
    }
    if (wi1 >= 0) {
        const float4* p = (const float4*)(bonds + (size_t)wi1 * 16);
#pragma unroll
        for (int c = 0; c < 4; c++) {
            float4 v = p[c];
            rows[1][4*c+0] = v.x; rows[1][4*c+1] = v.y; rows[1][4*c+2] = v.z; rows[1][4*c+3] = v.w;
        }
    }
    if (wi2 >= 0) {
        const float4* p = (const float4*)(bonds + (size_t)wi2 * 16);
#pragma unroll
        for (int c = 0; c < 4; c++) {
            float4 v = p[c];
            rows[2][4*c+0] = v.x; rows[2][4*c+1] = v.y; rows[2][4*c+2] = v.z; rows[2][4*c+3] = v.w;
        }
    }
    if (wi3 >= 0) {
        const float4* p = (const float4*)(bonds + (size_t)wi3 * 16);
#pragma unroll
        for (int c = 0; c < 4; c++) {
            float4 v = p[c];
            rows[3][4*c+0] = v.x; rows[3][4*c+1] = v.y; rows[3][4*c+2] = v.z; rows[3][4*c+3] = v.w;
        }
    }

    bool iv0 = (p2q * 4 + 0 >= len);
    bool iv1 = (p2q * 4 + 1 >= len);
    bool iv2 = (p2q * 4 + 2 >= len);
    bool iv3 = (p2q * 4 + 3 >= len);
    float* ob = out_ap + ((size_t)b * 16 * 128 + p1) * 128 + p2q * 4;
#pragma unroll
    for (int h = 0; h < 16; h++) {
        float4 v;
        v.x = iv0 ? NEG_BIG : rows[0][h];
        v.y = iv1 ? NEG_BIG : rows[1][h];
        v.z = iv2 ? NEG_BIG : rows[2][h];
        v.w = iv3 ? NEG_BIG : rows[3][h];
        *(float4*)(ob + (size_t)h * 16384) = v;
    }
}

// ================= K1: bonds | A-split(gather+pad+frag) | W-split(frag) | scatter | mask =================
__global__ __launch_bounds__(256) void k_phase1(
    const float* __restrict__ fB, const float* __restrict__ fBo,
    const float* __restrict__ Wb_raw, const float* __restrict__ b_bond,
    float* __restrict__ bonds_ws, int Nb,
    const float* __restrict__ fA, const float* __restrict__ fAo,
    short* __restrict__ AHf, short* __restrict__ ALf,
    const float* __restrict__ W, short* __restrict__ WHf, short* __restrict__ WLf,
    const int* __restrict__ b2a, const int* __restrict__ b2revb,
    const int* __restrict__ b_scope, int* __restrict__ winner,
    const int* __restrict__ a_scope, float* __restrict__ mask_out,
    int Bmol, int nBondsB, int nScatB)
{
    __shared__ char smem[33792];
    int bid = blockIdx.x;
    int tid = threadIdx.x;
    if (bid < nBondsB) {
        bonds_body(bid, smem, fB, fBo, Wb_raw, b_bond, bonds_ws, Nb);
        return;
    }
    bid -= nBondsB;
    if (bid < 4096) {
        // A-split: gather via a_scope, pad to 128 rows, f16x2-split, fragment order.
        int t = bid * 256 + tid;
        int l16 = t & 15, kq = (t >> 4) & 63, rt = (t >> 10) & 7, mol = t >> 13;
        int start = a_scope[2 * mol], len = a_scope[2 * mol + 1];
        int row = rt * 16 + l16;
        short8 h8, l8;
#pragma unroll
        for (int e = 0; e < 8; e++) { h8[e] = 0; l8[e] = 0; }
        if (row < len) {
            int kg = kq * 8;
            const float* p = (kg < 256) ? (fA + (size_t)(start + row) * 256 + kg)
                                        : (fAo + (size_t)(start + row) * 256 + (kg - 256));
            float4 v0 = ((const float4*)p)[0];
            float4 v1 = ((const float4*)p)[1];
            float xs[8] = {v0.x, v0.y, v0.z, v0.w, v1.x, v1.y, v1.z, v1.w};
#pragma unroll
            for (int e = 0; e < 8; e++) {
                short h = f2h(xs[e]);
                float r = (xs[e] - h2f(h)) * 2048.0f;
                h8[e] = h; l8[e] = f2h(r);
            }
        }
        size_t o = (size_t)mol * 65536 + (size_t)(rt * 64 + kq) * 128 + l16 * 8;
        *(short8*)(AHf + o) = h8;
        *(short8*)(ALf + o) = l8;
        return;
    }
    bid -= 4096;
    if (bid < 128) {
        // W-split: [k][n] fp32 -> fragment-ordered f16 hi + scaled-lo planes
        int t = bid * 256 + tid;
        int l16 = t & 15, kq = (t >> 4) & 63, nt = t >> 10;
        short8 h8, l8;
#pragma unroll
        for (int e = 0; e < 8; e++) {
            float x = W[(size_t)(kq * 8 + e) * 512 + nt * 16 + l16];
            short h = f2h(x);
            float r = (x - h2f(h)) * 2048.0f;
            h8[e] = h; l8[e] = f2h(r);
        }
        int o = (nt * 64 + kq) * 128 + l16 * 8;
        *(short8*)(WHf + o) = h8;
        *(short8*)(WLf + o) = l8;
        return;
    }
    bid -= 128;
    if (bid < nScatB) {
        scatter_body(bid, smem, b2a, b2revb, b_scope, winner, Nb, Bmol);
        return;
    }
    bid -= nScatB;
    {
        int t = bid * 256 + tid;
        if (t < Bmol * 128) {
            int b = t >> 7, p = t & 127;
            mask_out[t] = (p >= a_scope[2 * b + 1]) ? 1.0f : 0.0f;
        }
    }
}

// ================= K2: zero-LDS atoms GEMM | one-pass apairs =================
__global__ __launch_bounds__(256, 2) void k_phase2(
    const int* __restrict__ a_scope,
    const short* __restrict__ AHf, const short* __restrict__ ALf,
    const short* __restrict__ WHf, const short* __restrict__ WLf,
    const float* __restrict__ b_atom,
    const int* __restrict__ winner, const float* __restrict__ bonds_ws,
    float* __restrict__ out_emb, float* __restrict__ out_ap,
    int Bmol, int nAtomsB)
{
    int bid = blockIdx.x;
    if (bid < nAtomsB) {
        atoms_body(bid, a_scope, AHf, ALf, WHf, WLf, b_atom, out_emb, Bmol);
        return;
    }
    apairs_body(bid - nAtomsB, winner, bonds_ws, a_scope, out_ap);
}

extern "C" void kernel_launch(void* const* d_in, const int* in_sizes, int n_in,
                              void* d_out, int out_size, void* d_ws, size_t ws_size,
                              hipStream_t stream)
{
    const float* f_atoms     = (const float*)d_in[0];
    const float* f_bonds     = (const float*)d_in[1];
    const float* f_atoms_out = (const float*)d_in[2];
    const float* f_bonds_out = (const float*)d_in[3];
    const int*   b2a         = (const int*)d_in[4];
    const int*   b2revb      = (const int*)d_in[5];
    const int*   a_scope     = (const int*)d_in[6];
    const int*   b_scope     = (const int*)d_in[7];
    const float* W_atom      = (const float*)d_in[9];
    const float* b_atom      = (const float*)d_in[10];
    const float* W_bond      = (const float*)d_in[11];
    const float* b_bond      = (const float*)d_in[12];

    const int Bmol = in_sizes[6] / 2;   // 128
    const int Nb   = in_sizes[4];

    char* ws = (char*)d_ws;
    size_t off = 0;
    float* bonds_ws = (float*)(ws + off); off += ((size_t)Nb * 16 * 4 + 255) & ~(size_t)255;
    int*   winner   = (int*)(ws + off);   off += (size_t)Bmol * 16384 * 4;
    short* WHf      = (short*)(ws + off); off += 512 * 512 * 2;
    short* WLf      = (short*)(ws + off); off += 512 * 512 * 2;
    short* AHf      = (short*)(ws + off); off += (size_t)Bmol * 65536 * 2;
    short* ALf      = (short*)(ws + off); off += (size_t)Bmol * 65536 * 2;

    float* out_emb  = (float*)d_out;                                // (128, B, 512)
    float* out_ap   = out_emb + (size_t)128 * Bmol * 512;           // (B, 16, 128, 128)
    float* out_mask = out_ap + (size_t)Bmol * 16 * 128 * 128;       // (B, 128)

    // winner = -1 via byte pattern 0xFF (graph-capturable memset node)
    hipMemsetAsync(winner, 0xFF, (size_t)Bmol * 16384 * 4, stream);

    // K1: bonds GEMM | A-split | W-split | scatter | mask
    const int nBondsB = (Nb + 63) / 64;
    const int nScatB  = (Nb + 255) / 256;
    const int nMaskB  = (Bmol * 128 + 255) / 256;
    hipLaunchKernelGGL(k_phase1, dim3(nBondsB + 4096 + 128 + nScatB + nMaskB), dim3(256), 0, stream,
                       f_bonds, f_bonds_out, W_bond, b_bond, bonds_ws, Nb,
                       f_atoms, f_atoms_out, AHf, ALf,
                       W_atom, WHf, WLf,
                       b2a, b2revb, b_scope, winner,
                       a_scope, out_mask, Bmol, nBondsB, nScatB);

    // K2: zero-LDS atoms GEMM | one-pass apairs gather/write
    const int nAtomsB = 4 * Bmol;
    const int nApB    = Bmol * 4096 / 256;   // 2048
    hipLaunchKernelGGL(k_phase2, dim3(nAtomsB + nApB), dim3(256), 0, stream,
                       a_scope, AHf, ALf, WHf, WLf, b_atom,
                       winner, bonds_ws, out_emb, out_ap, Bmol, nAtomsB);
}